// Round 5
// baseline (139.793 us; speedup 1.0000x reference)
//
#include <hip/hip_runtime.h>

#define BB 32
#define LL 4096
#define DD 1024
#define CH 16      // rows per work chunk in k1
#define G1 2048    // k1 grid (all co-resident: 8 blocks/CU x 4 waves = 32 waves/CU)
#define SLOTS 12   // per-block partial slots: q<=4 batches crossed -> jloc<=3, 3 segs
#define K2_TILE 64
#define K3_TILE 32

static __device__ __forceinline__ int imax(int a, int b) { return a > b ? a : b; }
static __device__ __forceinline__ int imin(int a, int b) { return a < b ? a : b; }

// K0: zero hmid (BB*DD) and out (BB*DD) — the remaining atomic targets.
// 2*8192 float4 = 16384 -> 64 blocks x 256.
__global__ __launch_bounds__(256) void k0_zero(float* __restrict__ hmid,
                                               float* __restrict__ out) {
    const int i = blockIdx.x * 256 + threadIdx.x;
    const float4 z = make_float4(0.f, 0.f, 0.f, 0.f);
    if (i < 8192) ((float4*)hmid)[i] = z;
    else ((float4*)out)[i - 8192] = z;
}

// Add rows [beg,end) into acc, 4-deep unrolled (4 outstanding float4 loads).
static __device__ __forceinline__ void accum_rows_add(const float* __restrict__ hb,
                                                      int beg, int end, float4& acc) {
    float4 a0 = make_float4(0.f, 0.f, 0.f, 0.f);
    float4 a1 = make_float4(0.f, 0.f, 0.f, 0.f);
    float4 a2 = make_float4(0.f, 0.f, 0.f, 0.f);
    float4 a3 = make_float4(0.f, 0.f, 0.f, 0.f);
    int l = beg;
    for (; l + 4 <= end; l += 4) {
        float4 v0 = *(const float4*)(hb + (size_t)(l + 0) * DD);
        float4 v1 = *(const float4*)(hb + (size_t)(l + 1) * DD);
        float4 v2 = *(const float4*)(hb + (size_t)(l + 2) * DD);
        float4 v3 = *(const float4*)(hb + (size_t)(l + 3) * DD);
        a0.x += v0.x; a0.y += v0.y; a0.z += v0.z; a0.w += v0.w;
        a1.x += v1.x; a1.y += v1.y; a1.z += v1.z; a1.w += v1.w;
        a2.x += v2.x; a2.y += v2.y; a2.z += v2.z; a2.w += v2.w;
        a3.x += v3.x; a3.y += v3.y; a3.z += v3.z; a3.w += v3.w;
    }
    for (; l < end; ++l) {
        float4 v = *(const float4*)(hb + (size_t)l * DD);
        a0.x += v.x; a0.y += v.y; a0.z += v.z; a0.w += v.w;
    }
    acc.x += (a0.x + a1.x) + (a2.x + a3.x);
    acc.y += (a0.y + a1.y) + (a2.y + a3.y);
    acc.z += (a0.z + a1.z) + (a2.z + a3.z);
    acc.w += (a0.w + a1.w) + (a2.w + a3.w);
}

// K1: balanced flat chunks; ATOMIC-FREE. Each block stores per-(batch,seg)
// partials into its private slots part[blk][jloc*3+seg][DD]. Slot occupancy is
// deterministic arithmetic from the span indices (recomputed by k1c).
__global__ __launch_bounds__(256) void k1_sums(const float* __restrict__ h,
                                               const int* __restrict__ sp1,
                                               const int* __restrict__ sp2,
                                               float* __restrict__ part) {
    const int tid = threadIdx.x;

    int NC = 0;
#pragma unroll
    for (int b = 0; b < BB; ++b) {
        const int len = sp2[2 * b + 1] - sp1[2 * b] + 1;
        NC += (len + CH - 1) / CH;
    }
    const int q = (NC + G1 - 1) / G1;
    const int c0 = blockIdx.x * q;
    const int c1 = imin(c0 + q, NC);
    if (c0 >= c1) return;

    int b = 0, base = 0, s1, e1, s2, e2, ncb;
    for (;; ++b) {
        s1 = sp1[2 * b]; e1 = sp1[2 * b + 1];
        s2 = sp2[2 * b]; e2 = sp2[2 * b + 1];
        ncb = (e2 - s1 + 1 + CH - 1) / CH;
        if (c0 < base + ncb) break;
        base += ncb;
    }
    const int bfirst = b;
    const float* hb = h + (size_t)b * LL * DD + (size_t)tid * 4;
    float* slot0 = part + (size_t)blockIdx.x * SLOTS * DD + (size_t)tid * 4;

    int kcur = -1;
    float4 acc = make_float4(0.f, 0.f, 0.f, 0.f);
    for (int c = c0; c < c1; ++c) {
        if (c >= base + ncb) {
            base += ncb; ++b;
            s1 = sp1[2 * b]; e1 = sp1[2 * b + 1];
            s2 = sp2[2 * b]; e2 = sp2[2 * b + 1];
            ncb = (e2 - s1 + 1 + CH - 1) / CH;
            hb = h + (size_t)b * LL * DD + (size_t)tid * 4;
        }
        const int jloc = b - bfirst;
        const int beg = s1 + (c - base) * CH;
        const int end = imin(beg + CH, e2 + 1);
        const int lo[3] = {beg, imax(beg, e1 + 1), imax(beg, s2)};
        const int hi[3] = {imin(end, e1 + 1), imin(end, s2), end};
#pragma unroll
        for (int s = 0; s < 3; ++s) {
            if (lo[s] < hi[s]) {
                const int key = jloc * 3 + s;
                if (key != kcur) {
                    if (kcur >= 0) *(float4*)(slot0 + (size_t)kcur * DD) = acc;
                    kcur = key;
                    acc = make_float4(0.f, 0.f, 0.f, 0.f);
                }
                accum_rows_add(hb, lo[s], hi[s], acc);
            }
        }
    }
    if (kcur >= 0) *(float4*)(slot0 + (size_t)kcur * DD) = acc;
}

// K1c: one block per (b,seg) key; recompute which k1-blocks touched this key
// (pure arithmetic, identical clipping) and gather their slots. No atomics.
__global__ __launch_bounds__(256) void k1c_reduce(const float* __restrict__ part,
                                                  const int* __restrict__ sp1,
                                                  const int* __restrict__ sp2,
                                                  float* __restrict__ sums) {
    const int key = blockIdx.x;          // 0..95
    const int b = key / 3, s = key % 3;
    const int tid = threadIdx.x;

    int NC = 0, base_b = 0;
    for (int bb = 0; bb < BB; ++bb) {
        const int len = sp2[2 * bb + 1] - sp1[2 * bb] + 1;
        const int nc = (len + CH - 1) / CH;
        if (bb < b) base_b += nc;
        NC += nc;
    }
    const int s1 = sp1[2 * b], e1 = sp1[2 * b + 1];
    const int s2 = sp2[2 * b], e2 = sp2[2 * b + 1];
    const int ncb = (e2 - s1 + 1 + CH - 1) / CH;
    const int q = (NC + G1 - 1) / G1;
    const int lo_s = (s == 0) ? s1 : (s == 1) ? e1 + 1 : s2;
    const int hi_s = (s == 0) ? e1 + 1 : (s == 1) ? s2 : e2 + 1;

    const int bk_lo = base_b / q;
    const int bk_hi = (base_b + ncb - 1) / q;

    // batch index of chunk bk_lo*q (start of rolling advance)
    int bb = 0, bbase = 0;
    {
        const int c = bk_lo * q;
        for (;;) {
            const int len = sp2[2 * bb + 1] - sp1[2 * bb] + 1;
            const int nc = (len + CH - 1) / CH;
            if (c < bbase + nc) break;
            bbase += nc; ++bb;
        }
    }

    float4 a0 = make_float4(0.f, 0.f, 0.f, 0.f);
    float4 a1 = a0, a2 = a0, a3 = a0;
    const float4 z = a0;

    for (int bk = bk_lo; bk <= bk_hi; bk += 4) {
        const float* p0 = nullptr; const float* p1 = nullptr;
        const float* p2 = nullptr; const float* p3 = nullptr;
#pragma unroll
        for (int u = 0; u < 4; ++u) {
            const int bkk = bk + u;
            if (bkk > bk_hi) break;
            const int cc0 = bkk * q;
            const int cc1 = imin(cc0 + q, NC);
            for (;;) {  // advance bb to batch containing cc0
                const int len = sp2[2 * bb + 1] - sp1[2 * bb] + 1;
                const int nc = (len + CH - 1) / CH;
                if (cc0 < bbase + nc) break;
                bbase += nc; ++bb;
            }
            const int clo = imax(cc0, base_b);
            const int chi = imin(cc1, base_b + ncb);
            if (clo >= chi) continue;
            const int rbeg = s1 + (clo - base_b) * CH;
            const int rend = imin(s1 + (chi - base_b) * CH, e2 + 1);
            const int beg = imax(rbeg, lo_s);
            const int end = imin(rend, hi_s);
            if (beg < end) {
                const int slot = (b - bb) * 3 + s;
                const float* p = part + ((size_t)bkk * SLOTS + slot) * DD + (size_t)tid * 4;
                if (u == 0) p0 = p; else if (u == 1) p1 = p; else if (u == 2) p2 = p; else p3 = p;
            }
        }
        const float4 v0 = p0 ? *(const float4*)p0 : z;
        const float4 v1 = p1 ? *(const float4*)p1 : z;
        const float4 v2 = p2 ? *(const float4*)p2 : z;
        const float4 v3 = p3 ? *(const float4*)p3 : z;
        a0.x += v0.x; a0.y += v0.y; a0.z += v0.z; a0.w += v0.w;
        a1.x += v1.x; a1.y += v1.y; a1.z += v1.z; a1.w += v1.w;
        a2.x += v2.x; a2.y += v2.y; a2.z += v2.z; a2.w += v2.w;
        a3.x += v3.x; a3.y += v3.y; a3.z += v3.z; a3.w += v3.w;
    }
    float4 r;
    r.x = (a0.x + a1.x) + (a2.x + a3.x);
    r.y = (a0.y + a1.y) + (a2.y + a3.y);
    r.z = (a0.z + a1.z) + (a2.z + a3.z);
    r.w = (a0.w + a1.w) + (a2.w + a3.w);
    *(float4*)(sums + ((size_t)b * 3 + s) * DD + (size_t)tid * 4) = r;
}

// K2 (k1b folded in): hmid[b][j] += sum_{k in tile} (sums[b][k]*ic) * W1[k][j]
__global__ __launch_bounds__(256) void k2_gemm1(const float* __restrict__ sums,
                                                const int* __restrict__ sp1,
                                                const int* __restrict__ sp2,
                                                const float* __restrict__ W1,
                                                float* __restrict__ hmid) {
    __shared__ float cl[K2_TILE * BB];  // [kk][b]
    __shared__ float icl[BB];
    const int tid = threadIdx.x;
    const int j = blockIdx.x * 256 + tid;
    const int k0 = blockIdx.y * K2_TILE;
    const int seg = k0 / DD;

    if (tid < BB) {
        const int b = tid;
        const int s1 = sp1[2 * b], e1 = sp1[2 * b + 1];
        const int s2 = sp2[2 * b], e2 = sp2[2 * b + 1];
        const int cnt = (seg == 0) ? (e1 + 1 - s1) : (seg == 1) ? (s2 - e1 - 1) : (e2 + 1 - s2);
        icl[b] = 1.0f / (float)imax(cnt, 1);
    }
    __syncthreads();
    for (int i = tid; i < K2_TILE * BB; i += 256) {
        const int kk = i / BB;
        const int b = i % BB;
        cl[i] = sums[(size_t)b * (3 * DD) + (k0 + kk)] * icl[b];
    }
    __syncthreads();

    float acc[BB];
#pragma unroll
    for (int b = 0; b < BB; ++b) acc[b] = 0.f;

    const float* w = W1 + (size_t)k0 * DD + j;
    for (int kk = 0; kk < K2_TILE; ++kk) {
        const float wv = w[(size_t)kk * DD];
        const float4* c4 = (const float4*)(cl + kk * BB);
#pragma unroll
        for (int qq = 0; qq < BB / 4; ++qq) {
            float4 c = c4[qq];
            acc[4 * qq + 0] = fmaf(c.x, wv, acc[4 * qq + 0]);
            acc[4 * qq + 1] = fmaf(c.y, wv, acc[4 * qq + 1]);
            acc[4 * qq + 2] = fmaf(c.z, wv, acc[4 * qq + 2]);
            acc[4 * qq + 3] = fmaf(c.w, wv, acc[4 * qq + 3]);
        }
    }
#pragma unroll
    for (int b = 0; b < BB; ++b) atomicAdd(&hmid[(size_t)b * DD + j], acc[b]);
}

// K3: out[b][j] += sum_{k in tile} relu(hmid[b][k]+b1[k]) * W2[k][j]  (+ b2 once)
__global__ __launch_bounds__(256) void k3_gemm2(const float* __restrict__ hmid,
                                                const float* __restrict__ b1,
                                                const float* __restrict__ W2,
                                                const float* __restrict__ b2,
                                                float* __restrict__ out) {
    __shared__ float al[K3_TILE * BB];  // [kk][b]
    const int tid = threadIdx.x;
    const int j = blockIdx.x * 256 + tid;
    const int k0 = blockIdx.y * K3_TILE;

    for (int i = tid; i < K3_TILE * BB; i += 256) {
        const int kk = i / BB;
        const int b = i % BB;
        const float v = hmid[(size_t)b * DD + (k0 + kk)] + b1[k0 + kk];
        al[i] = fmaxf(v, 0.f);
    }
    __syncthreads();

    float acc[BB];
    const float bias = (blockIdx.y == 0) ? b2[j] : 0.f;
#pragma unroll
    for (int b = 0; b < BB; ++b) acc[b] = bias;

    const float* w = W2 + (size_t)k0 * DD + j;
    for (int kk = 0; kk < K3_TILE; ++kk) {
        const float wv = w[(size_t)kk * DD];
        const float4* c4 = (const float4*)(al + kk * BB);
#pragma unroll
        for (int qq = 0; qq < BB / 4; ++qq) {
            float4 c = c4[qq];
            acc[4 * qq + 0] = fmaf(c.x, wv, acc[4 * qq + 0]);
            acc[4 * qq + 1] = fmaf(c.y, wv, acc[4 * qq + 1]);
            acc[4 * qq + 2] = fmaf(c.z, wv, acc[4 * qq + 2]);
            acc[4 * qq + 3] = fmaf(c.w, wv, acc[4 * qq + 3]);
        }
    }
#pragma unroll
    for (int b = 0; b < BB; ++b) atomicAdd(&out[(size_t)b * DD + j], acc[b]);
}

extern "C" void kernel_launch(void* const* d_in, const int* in_sizes, int n_in,
                              void* d_out, int out_size, void* d_ws, size_t ws_size,
                              hipStream_t stream) {
    const float* h = (const float*)d_in[0];
    const int* sp1 = (const int*)d_in[1];
    const int* sp2 = (const int*)d_in[2];
    const float* W1 = (const float*)d_in[3];
    const float* b1 = (const float*)d_in[4];
    const float* W2 = (const float*)d_in[5];
    const float* b2 = (const float*)d_in[6];
    float* out = (float*)d_out;

    float* sums = (float*)d_ws;                    // B*3*D floats
    float* hmid = sums + BB * 3 * DD;              // B*D floats
    float* part = hmid + BB * DD;                  // G1*SLOTS*D floats (~100 MB)

    k0_zero<<<64, 256, 0, stream>>>(hmid, out);
    k1_sums<<<G1, 256, 0, stream>>>(h, sp1, sp2, part);
    k1c_reduce<<<96, 256, 0, stream>>>(part, sp1, sp2, sums);
    k2_gemm1<<<dim3(DD / 256, 3 * DD / K2_TILE), 256, 0, stream>>>(sums, sp1, sp2, W1, hmid);
    k3_gemm2<<<dim3(DD / 256, DD / K3_TILE), 256, 0, stream>>>(hmid, b1, W2, b2, out);
}

// Round 6
// 125.365 us; speedup vs baseline: 1.1151x; 1.1151x over previous
//
#include <hip/hip_runtime.h>

#define BB 32
#define LL 4096
#define DD 1024
#define CH 16      // rows per work chunk in k1
#define G1 2048    // k1 grid, all co-resident (8 blocks/CU x 4 waves)
#define K2_TILE 64
#define K3_TILE 32
#define NY2 (3 * DD / K2_TILE)   // 48 k-tiles in GEMM1
#define NY3 (DD / K3_TILE)       // 32 k-tiles in GEMM2

static __device__ __forceinline__ int imax(int a, int b) { return a > b ? a : b; }
static __device__ __forceinline__ int imin(int a, int b) { return a < b ? a : b; }

// K0: zero sums (BB*3*DD floats = 24576 float4) — the only atomic target left.
__global__ __launch_bounds__(256) void k0_zero(float* __restrict__ sums) {
    ((float4*)sums)[blockIdx.x * 256 + threadIdx.x] = make_float4(0.f, 0.f, 0.f, 0.f);
}

// Add rows [beg,end) into acc, 4-deep unrolled (4 outstanding float4 loads).
static __device__ __forceinline__ void accum_rows_add(const float* __restrict__ hb,
                                                      int beg, int end, float4& acc) {
    float4 a0 = make_float4(0.f, 0.f, 0.f, 0.f);
    float4 a1 = make_float4(0.f, 0.f, 0.f, 0.f);
    float4 a2 = make_float4(0.f, 0.f, 0.f, 0.f);
    float4 a3 = make_float4(0.f, 0.f, 0.f, 0.f);
    int l = beg;
    for (; l + 4 <= end; l += 4) {
        float4 v0 = *(const float4*)(hb + (size_t)(l + 0) * DD);
        float4 v1 = *(const float4*)(hb + (size_t)(l + 1) * DD);
        float4 v2 = *(const float4*)(hb + (size_t)(l + 2) * DD);
        float4 v3 = *(const float4*)(hb + (size_t)(l + 3) * DD);
        a0.x += v0.x; a0.y += v0.y; a0.z += v0.z; a0.w += v0.w;
        a1.x += v1.x; a1.y += v1.y; a1.z += v1.z; a1.w += v1.w;
        a2.x += v2.x; a2.y += v2.y; a2.z += v2.z; a2.w += v2.w;
        a3.x += v3.x; a3.y += v3.y; a3.z += v3.z; a3.w += v3.w;
    }
    for (; l < end; ++l) {
        float4 v = *(const float4*)(hb + (size_t)l * DD);
        a0.x += v.x; a0.y += v.y; a0.z += v.z; a0.w += v.w;
    }
    acc.x += (a0.x + a1.x) + (a2.x + a3.x);
    acc.y += (a0.y + a1.y) + (a2.y + a3.y);
    acc.z += (a0.z + a1.z) + (a2.z + a3.z);
    acc.w += (a0.w + a1.w) + (a2.w + a3.w);
}

// K1 (R4 form, exact remainder balance): per-span sums via register accum +
// flush-on-key-change atomics into sums[B][3][D].
__global__ __launch_bounds__(256) void k1_sums(const float* __restrict__ h,
                                               const int* __restrict__ sp1,
                                               const int* __restrict__ sp2,
                                               float* __restrict__ sums) {
    const int tid = threadIdx.x;

    int NC = 0;
#pragma unroll
    for (int b = 0; b < BB; ++b) {
        const int len = sp2[2 * b + 1] - sp1[2 * b] + 1;
        NC += (len + CH - 1) / CH;
    }
    const int q = NC / G1, r = NC % G1;
    const int bk = blockIdx.x;
    const int c0 = bk * q + imin(bk, r);
    const int c1 = c0 + q + (bk < r ? 1 : 0);
    if (c0 >= c1) return;

    int b = 0, base = 0, s1, e1, s2, e2, ncb;
    for (;; ++b) {
        s1 = sp1[2 * b]; e1 = sp1[2 * b + 1];
        s2 = sp2[2 * b]; e2 = sp2[2 * b + 1];
        ncb = (e2 - s1 + 1 + CH - 1) / CH;
        if (c0 < base + ncb) break;
        base += ncb;
    }
    const float* hb = h + (size_t)b * LL * DD + (size_t)tid * 4;
    float* dstb = sums + (size_t)b * 3 * DD + (size_t)tid * 4;

    float* kdst = nullptr;
    float4 acc = make_float4(0.f, 0.f, 0.f, 0.f);
    for (int c = c0; c < c1; ++c) {
        if (c >= base + ncb) {
            base += ncb; ++b;
            s1 = sp1[2 * b]; e1 = sp1[2 * b + 1];
            s2 = sp2[2 * b]; e2 = sp2[2 * b + 1];
            ncb = (e2 - s1 + 1 + CH - 1) / CH;
            hb = h + (size_t)b * LL * DD + (size_t)tid * 4;
            dstb = sums + (size_t)b * 3 * DD + (size_t)tid * 4;
        }
        const int beg = s1 + (c - base) * CH;
        const int end = imin(beg + CH, e2 + 1);
        const int lo[3] = {beg, imax(beg, e1 + 1), imax(beg, s2)};
        const int hi[3] = {imin(end, e1 + 1), imin(end, s2), end};
#pragma unroll
        for (int s = 0; s < 3; ++s) {
            if (lo[s] < hi[s]) {
                float* d = dstb + s * DD;
                if (d != kdst) {
                    if (kdst) {
                        atomicAdd(kdst + 0, acc.x); atomicAdd(kdst + 1, acc.y);
                        atomicAdd(kdst + 2, acc.z); atomicAdd(kdst + 3, acc.w);
                    }
                    kdst = d;
                    acc = make_float4(0.f, 0.f, 0.f, 0.f);
                }
                accum_rows_add(hb, lo[s], hi[s], acc);
            }
        }
    }
    if (kdst) {
        atomicAdd(kdst + 0, acc.x); atomicAdd(kdst + 1, acc.y);
        atomicAdd(kdst + 2, acc.z); atomicAdd(kdst + 3, acc.w);
    }
}

// K2: ATOMIC-FREE partials. part2[(y*BB+b)*DD + j] = sum_{k in tile y} (sums*ic) * W1[k][j]
__global__ __launch_bounds__(256) void k2_gemm1(const float* __restrict__ sums,
                                                const int* __restrict__ sp1,
                                                const int* __restrict__ sp2,
                                                const float* __restrict__ W1,
                                                float* __restrict__ part2) {
    __shared__ float cl[K2_TILE * BB];  // [kk][b]
    __shared__ float icl[BB];
    const int tid = threadIdx.x;
    const int j = blockIdx.x * 256 + tid;
    const int k0 = blockIdx.y * K2_TILE;
    const int seg = k0 / DD;

    if (tid < BB) {
        const int b = tid;
        const int s1 = sp1[2 * b], e1 = sp1[2 * b + 1];
        const int s2 = sp2[2 * b], e2 = sp2[2 * b + 1];
        const int cnt = (seg == 0) ? (e1 + 1 - s1) : (seg == 1) ? (s2 - e1 - 1) : (e2 + 1 - s2);
        icl[b] = 1.0f / (float)imax(cnt, 1);
    }
    __syncthreads();
    for (int i = tid; i < K2_TILE * BB; i += 256) {
        const int kk = i / BB;
        const int b = i % BB;
        cl[i] = sums[(size_t)b * (3 * DD) + (k0 + kk)] * icl[b];
    }
    __syncthreads();

    float acc[BB];
#pragma unroll
    for (int b = 0; b < BB; ++b) acc[b] = 0.f;

    const float* w = W1 + (size_t)k0 * DD + j;
#pragma unroll 4
    for (int kk = 0; kk < K2_TILE; ++kk) {
        const float wv = w[(size_t)kk * DD];
        const float4* c4 = (const float4*)(cl + kk * BB);
#pragma unroll
        for (int qq = 0; qq < BB / 4; ++qq) {
            float4 c = c4[qq];
            acc[4 * qq + 0] = fmaf(c.x, wv, acc[4 * qq + 0]);
            acc[4 * qq + 1] = fmaf(c.y, wv, acc[4 * qq + 1]);
            acc[4 * qq + 2] = fmaf(c.z, wv, acc[4 * qq + 2]);
            acc[4 * qq + 3] = fmaf(c.w, wv, acc[4 * qq + 3]);
        }
    }
    float* p = part2 + ((size_t)blockIdx.y * BB) * DD + j;
#pragma unroll
    for (int b = 0; b < BB; ++b) p[(size_t)b * DD] = acc[b];
}

// K2b: hmid[b][j] = relu(b1[j] + sum_{y=0..47} part2[(y*BB+b)*DD + j])
__global__ __launch_bounds__(256) void k2b_reduce(const float* __restrict__ part2,
                                                  const float* __restrict__ b1,
                                                  float* __restrict__ hmid) {
    const int j = blockIdx.x * 256 + threadIdx.x;
    const int b = blockIdx.y;
    const float* p = part2 + (size_t)b * DD + j;
    float s0 = 0.f, s1 = 0.f, s2 = 0.f, s3 = 0.f;
#pragma unroll
    for (int y = 0; y < NY2; y += 4) {
        s0 += p[(size_t)(y + 0) * BB * DD];
        s1 += p[(size_t)(y + 1) * BB * DD];
        s2 += p[(size_t)(y + 2) * BB * DD];
        s3 += p[(size_t)(y + 3) * BB * DD];
    }
    hmid[(size_t)b * DD + j] = fmaxf((s0 + s1) + (s2 + s3) + b1[j], 0.f);
}

// K3: ATOMIC-FREE partials. part3[(y*BB+b)*DD + j] = sum_{k in tile y} hmid[b][k] * W2[k][j]
__global__ __launch_bounds__(256) void k3_gemm2(const float* __restrict__ hmid,
                                                const float* __restrict__ W2,
                                                float* __restrict__ part3) {
    __shared__ float al[K3_TILE * BB];  // [kk][b]
    const int tid = threadIdx.x;
    const int j = blockIdx.x * 256 + tid;
    const int k0 = blockIdx.y * K3_TILE;

    for (int i = tid; i < K3_TILE * BB; i += 256) {
        const int kk = i / BB;
        const int b = i % BB;
        al[i] = hmid[(size_t)b * DD + (k0 + kk)];
    }
    __syncthreads();

    float acc[BB];
#pragma unroll
    for (int b = 0; b < BB; ++b) acc[b] = 0.f;

    const float* w = W2 + (size_t)k0 * DD + j;
#pragma unroll 4
    for (int kk = 0; kk < K3_TILE; ++kk) {
        const float wv = w[(size_t)kk * DD];
        const float4* c4 = (const float4*)(al + kk * BB);
#pragma unroll
        for (int qq = 0; qq < BB / 4; ++qq) {
            float4 c = c4[qq];
            acc[4 * qq + 0] = fmaf(c.x, wv, acc[4 * qq + 0]);
            acc[4 * qq + 1] = fmaf(c.y, wv, acc[4 * qq + 1]);
            acc[4 * qq + 2] = fmaf(c.z, wv, acc[4 * qq + 2]);
            acc[4 * qq + 3] = fmaf(c.w, wv, acc[4 * qq + 3]);
        }
    }
    float* p = part3 + ((size_t)blockIdx.y * BB) * DD + j;
#pragma unroll
    for (int b = 0; b < BB; ++b) p[(size_t)b * DD] = acc[b];
}

// K3b: out[b][j] = b2[j] + sum_{y=0..31} part3[(y*BB+b)*DD + j]
__global__ __launch_bounds__(256) void k3b_reduce(const float* __restrict__ part3,
                                                  const float* __restrict__ b2,
                                                  float* __restrict__ out) {
    const int j = blockIdx.x * 256 + threadIdx.x;
    const int b = blockIdx.y;
    const float* p = part3 + (size_t)b * DD + j;
    float s0 = 0.f, s1 = 0.f, s2 = 0.f, s3 = 0.f;
#pragma unroll
    for (int y = 0; y < NY3; y += 4) {
        s0 += p[(size_t)(y + 0) * BB * DD];
        s1 += p[(size_t)(y + 1) * BB * DD];
        s2 += p[(size_t)(y + 2) * BB * DD];
        s3 += p[(size_t)(y + 3) * BB * DD];
    }
    out[(size_t)b * DD + j] = (s0 + s1) + (s2 + s3) + b2[j];
}

extern "C" void kernel_launch(void* const* d_in, const int* in_sizes, int n_in,
                              void* d_out, int out_size, void* d_ws, size_t ws_size,
                              hipStream_t stream) {
    const float* h = (const float*)d_in[0];
    const int* sp1 = (const int*)d_in[1];
    const int* sp2 = (const int*)d_in[2];
    const float* W1 = (const float*)d_in[3];
    const float* b1 = (const float*)d_in[4];
    const float* W2 = (const float*)d_in[5];
    const float* b2 = (const float*)d_in[6];
    float* out = (float*)d_out;

    float* sums = (float*)d_ws;                     // BB*3*DD
    float* hmid = sums + BB * 3 * DD;               // BB*DD
    float* part2 = hmid + BB * DD;                  // NY2*BB*DD (6 MB)
    float* part3 = part2 + (size_t)NY2 * BB * DD;   // NY3*BB*DD (4 MB)

    k0_zero<<<96, 256, 0, stream>>>(sums);
    k1_sums<<<G1, 256, 0, stream>>>(h, sp1, sp2, sums);
    k2_gemm1<<<dim3(DD / 256, NY2), 256, 0, stream>>>(sums, sp1, sp2, W1, part2);
    k2b_reduce<<<dim3(DD / 256, BB), 256, 0, stream>>>(part2, b1, hmid);
    k3_gemm2<<<dim3(DD / 256, NY3), 256, 0, stream>>>(hmid, W2, part3);
    k3b_reduce<<<dim3(DD / 256, BB), 256, 0, stream>>>(part3, b2, out);
}

// Round 7
// 111.907 us; speedup vs baseline: 1.2492x; 1.1203x over previous
//
#include <hip/hip_runtime.h>

#define BB 32
#define LL 4096
#define DD 1024
#define G1 1024    // k1 grid: 4 blocks/CU, 16 waves/CU
#define K2_TILE 64
#define K3_TILE 32

static __device__ __forceinline__ int imax(int a, int b) { return a > b ? a : b; }
static __device__ __forceinline__ int imin(int a, int b) { return a < b ? a : b; }

// K0: zero sums (24576 f4) + hmid (8192 f4) + out (8192 f4) = 40960 float4.
__global__ __launch_bounds__(256) void k0_zero(float* __restrict__ sums_hmid,
                                               float* __restrict__ out) {
    const int i = blockIdx.x * 256 + threadIdx.x;
    const float4 z = make_float4(0.f, 0.f, 0.f, 0.f);
    if (i < 32768) ((float4*)sums_hmid)[i] = z;
    else ((float4*)out)[i - 32768] = z;
}

// Add rows [beg,end) into acc: 8-deep then 4-deep then scalar tail.
static __device__ __forceinline__ void accum_rows_add(const float* __restrict__ hb,
                                                      int beg, int end, float4& acc) {
    float4 a0 = make_float4(0.f, 0.f, 0.f, 0.f);
    float4 a1 = a0, a2 = a0, a3 = a0, a4 = a0, a5 = a0, a6 = a0, a7 = a0;
    int l = beg;
    for (; l + 8 <= end; l += 8) {
        float4 v0 = *(const float4*)(hb + (size_t)(l + 0) * DD);
        float4 v1 = *(const float4*)(hb + (size_t)(l + 1) * DD);
        float4 v2 = *(const float4*)(hb + (size_t)(l + 2) * DD);
        float4 v3 = *(const float4*)(hb + (size_t)(l + 3) * DD);
        float4 v4 = *(const float4*)(hb + (size_t)(l + 4) * DD);
        float4 v5 = *(const float4*)(hb + (size_t)(l + 5) * DD);
        float4 v6 = *(const float4*)(hb + (size_t)(l + 6) * DD);
        float4 v7 = *(const float4*)(hb + (size_t)(l + 7) * DD);
        a0.x += v0.x; a0.y += v0.y; a0.z += v0.z; a0.w += v0.w;
        a1.x += v1.x; a1.y += v1.y; a1.z += v1.z; a1.w += v1.w;
        a2.x += v2.x; a2.y += v2.y; a2.z += v2.z; a2.w += v2.w;
        a3.x += v3.x; a3.y += v3.y; a3.z += v3.z; a3.w += v3.w;
        a4.x += v4.x; a4.y += v4.y; a4.z += v4.z; a4.w += v4.w;
        a5.x += v5.x; a5.y += v5.y; a5.z += v5.z; a5.w += v5.w;
        a6.x += v6.x; a6.y += v6.y; a6.z += v6.z; a6.w += v6.w;
        a7.x += v7.x; a7.y += v7.y; a7.z += v7.z; a7.w += v7.w;
    }
    for (; l + 4 <= end; l += 4) {
        float4 v0 = *(const float4*)(hb + (size_t)(l + 0) * DD);
        float4 v1 = *(const float4*)(hb + (size_t)(l + 1) * DD);
        float4 v2 = *(const float4*)(hb + (size_t)(l + 2) * DD);
        float4 v3 = *(const float4*)(hb + (size_t)(l + 3) * DD);
        a0.x += v0.x; a0.y += v0.y; a0.z += v0.z; a0.w += v0.w;
        a1.x += v1.x; a1.y += v1.y; a1.z += v1.z; a1.w += v1.w;
        a2.x += v2.x; a2.y += v2.y; a2.z += v2.z; a2.w += v2.w;
        a3.x += v3.x; a3.y += v3.y; a3.z += v3.z; a3.w += v3.w;
    }
    for (; l < end; ++l) {
        float4 v = *(const float4*)(hb + (size_t)l * DD);
        a0.x += v.x; a0.y += v.y; a0.z += v.z; a0.w += v.w;
    }
    acc.x += ((a0.x + a1.x) + (a2.x + a3.x)) + ((a4.x + a5.x) + (a6.x + a7.x));
    acc.y += ((a0.y + a1.y) + (a2.y + a3.y)) + ((a4.y + a5.y) + (a6.y + a7.y));
    acc.z += ((a0.z + a1.z) + (a2.z + a3.z)) + ((a4.z + a5.z) + (a6.z + a7.z));
    acc.w += ((a0.w + a1.w) + (a2.w + a3.w)) + ((a4.w + a5.w) + (a6.w + a7.w));
}

// K1: row-granular balanced decomposition (CH=1). Work units = rows of the
// union span [s1,e2] per batch; block gets a contiguous row range (spread
// <=1 row). Per (batch,seg) piece: one merged accum + one 4-atomic flush.
__global__ __launch_bounds__(256) void k1_sums(const float* __restrict__ h,
                                               const int* __restrict__ sp1,
                                               const int* __restrict__ sp2,
                                               float* __restrict__ sums) {
    const int tid = threadIdx.x;

    int NC = 0;
#pragma unroll
    for (int b = 0; b < BB; ++b)
        NC += sp2[2 * b + 1] - sp1[2 * b] + 1;

    const int q = NC / G1, r = NC % G1;
    const int bk = blockIdx.x;
    int c0 = bk * q + imin(bk, r);
    const int c1 = c0 + q + (bk < r ? 1 : 0);
    if (c0 >= c1) return;

    int b = 0, base = 0, s1, e1, s2, e2, len;
    for (;; ++b) {
        s1 = sp1[2 * b]; e1 = sp1[2 * b + 1];
        s2 = sp2[2 * b]; e2 = sp2[2 * b + 1];
        len = e2 - s1 + 1;
        if (c0 < base + len) break;
        base += len;
    }

    for (;;) {
        const int cend = imin(c1, base + len);
        const int rb = s1 + (c0 - base);
        const int re = s1 + (cend - base);
        const float* hb = h + (size_t)b * LL * DD + (size_t)tid * 4;
        float* dstb = sums + (size_t)b * 3 * DD + (size_t)tid * 4;
        const int lo[3] = {rb, imax(rb, e1 + 1), imax(rb, s2)};
        const int hi[3] = {imin(re, e1 + 1), imin(re, s2), re};
#pragma unroll
        for (int s = 0; s < 3; ++s) {
            if (lo[s] < hi[s]) {
                float4 acc = make_float4(0.f, 0.f, 0.f, 0.f);
                accum_rows_add(hb, lo[s], hi[s], acc);
                float* d = dstb + s * DD;
                atomicAdd(d + 0, acc.x); atomicAdd(d + 1, acc.y);
                atomicAdd(d + 2, acc.z); atomicAdd(d + 3, acc.w);
            }
        }
        c0 = cend;
        if (c0 >= c1) break;
        base += len; ++b;
        s1 = sp1[2 * b]; e1 = sp1[2 * b + 1];
        s2 = sp2[2 * b]; e2 = sp2[2 * b + 1];
        len = e2 - s1 + 1;
    }
}

// K2 (k1b folded): hmid[b][j] += sum_{k in tile} (sums[b][k]*ic) * W1[k][j]
__global__ __launch_bounds__(256) void k2_gemm1(const float* __restrict__ sums,
                                                const int* __restrict__ sp1,
                                                const int* __restrict__ sp2,
                                                const float* __restrict__ W1,
                                                float* __restrict__ hmid) {
    __shared__ float cl[K2_TILE * BB];  // [kk][b]
    __shared__ float icl[BB];
    const int tid = threadIdx.x;
    const int j = blockIdx.x * 256 + tid;
    const int k0 = blockIdx.y * K2_TILE;
    const int seg = k0 / DD;

    if (tid < BB) {
        const int b = tid;
        const int s1 = sp1[2 * b], e1 = sp1[2 * b + 1];
        const int s2 = sp2[2 * b], e2 = sp2[2 * b + 1];
        const int cnt = (seg == 0) ? (e1 + 1 - s1) : (seg == 1) ? (s2 - e1 - 1) : (e2 + 1 - s2);
        icl[b] = 1.0f / (float)imax(cnt, 1);
    }
    __syncthreads();
    for (int i = tid; i < K2_TILE * BB; i += 256) {
        const int kk = i / BB;
        const int b = i % BB;
        cl[i] = sums[(size_t)b * (3 * DD) + (k0 + kk)] * icl[b];
    }
    __syncthreads();

    float acc[BB];
#pragma unroll
    for (int b = 0; b < BB; ++b) acc[b] = 0.f;

    const float* w = W1 + (size_t)k0 * DD + j;
#pragma unroll 4
    for (int kk = 0; kk < K2_TILE; ++kk) {
        const float wv = w[(size_t)kk * DD];
        const float4* c4 = (const float4*)(cl + kk * BB);
#pragma unroll
        for (int qq = 0; qq < BB / 4; ++qq) {
            float4 c = c4[qq];
            acc[4 * qq + 0] = fmaf(c.x, wv, acc[4 * qq + 0]);
            acc[4 * qq + 1] = fmaf(c.y, wv, acc[4 * qq + 1]);
            acc[4 * qq + 2] = fmaf(c.z, wv, acc[4 * qq + 2]);
            acc[4 * qq + 3] = fmaf(c.w, wv, acc[4 * qq + 3]);
        }
    }
#pragma unroll
    for (int b = 0; b < BB; ++b) atomicAdd(&hmid[(size_t)b * DD + j], acc[b]);
}

// K3: out[b][j] += sum_{k in tile} relu(hmid[b][k]+b1[k]) * W2[k][j]  (+ b2 once)
__global__ __launch_bounds__(256) void k3_gemm2(const float* __restrict__ hmid,
                                                const float* __restrict__ b1,
                                                const float* __restrict__ W2,
                                                const float* __restrict__ b2,
                                                float* __restrict__ out) {
    __shared__ float al[K3_TILE * BB];  // [kk][b]
    const int tid = threadIdx.x;
    const int j = blockIdx.x * 256 + tid;
    const int k0 = blockIdx.y * K3_TILE;

    for (int i = tid; i < K3_TILE * BB; i += 256) {
        const int kk = i / BB;
        const int b = i % BB;
        const float v = hmid[(size_t)b * DD + (k0 + kk)] + b1[k0 + kk];
        al[i] = fmaxf(v, 0.f);
    }
    __syncthreads();

    float acc[BB];
    const float bias = (blockIdx.y == 0) ? b2[j] : 0.f;
#pragma unroll
    for (int b = 0; b < BB; ++b) acc[b] = bias;

    const float* w = W2 + (size_t)k0 * DD + j;
#pragma unroll 4
    for (int kk = 0; kk < K3_TILE; ++kk) {
        const float wv = w[(size_t)kk * DD];
        const float4* c4 = (const float4*)(al + kk * BB);
#pragma unroll
        for (int qq = 0; qq < BB / 4; ++qq) {
            float4 c = c4[qq];
            acc[4 * qq + 0] = fmaf(c.x, wv, acc[4 * qq + 0]);
            acc[4 * qq + 1] = fmaf(c.y, wv, acc[4 * qq + 1]);
            acc[4 * qq + 2] = fmaf(c.z, wv, acc[4 * qq + 2]);
            acc[4 * qq + 3] = fmaf(c.w, wv, acc[4 * qq + 3]);
        }
    }
#pragma unroll
    for (int b = 0; b < BB; ++b) atomicAdd(&out[(size_t)b * DD + j], acc[b]);
}

extern "C" void kernel_launch(void* const* d_in, const int* in_sizes, int n_in,
                              void* d_out, int out_size, void* d_ws, size_t ws_size,
                              hipStream_t stream) {
    const float* h = (const float*)d_in[0];
    const int* sp1 = (const int*)d_in[1];
    const int* sp2 = (const int*)d_in[2];
    const float* W1 = (const float*)d_in[3];
    const float* b1 = (const float*)d_in[4];
    const float* W2 = (const float*)d_in[5];
    const float* b2 = (const float*)d_in[6];
    float* out = (float*)d_out;

    float* sums = (float*)d_ws;            // BB*3*DD floats
    float* hmid = sums + BB * 3 * DD;      // BB*DD floats (contiguous after sums)

    k0_zero<<<160, 256, 0, stream>>>((float*)d_ws, out);
    k1_sums<<<G1, 256, 0, stream>>>(h, sp1, sp2, sums);
    k2_gemm1<<<dim3(DD / 256, 3 * DD / K2_TILE), 256, 0, stream>>>(sums, sp1, sp2, W1, hmid);
    k3_gemm2<<<dim3(DD / 256, DD / K3_TILE), 256, 0, stream>>>(hmid, b1, W2, b2, out);
}